// Round 1
// baseline (107.202 us; speedup 1.0000x reference)
//
#include <hip/hip_runtime.h>
#include <math.h>

// Problem constants (B, D, C) from the reference.
#define NB 4096
#define ND 3072
#define NC 10
#define NM 9   // C-1

static constexpr float kEps      = 0.1f;
static constexpr float kNumStab  = 1e-6f;
static constexpr float kAlpha    = 1.0f - (float)NC * kNumStab;  // 1 - C*num_stab
static constexpr float kInvSqrtC = 0.31622776601683794f;         // 1/sqrt(10)

// ---------------------------------------------------------------------------
// Kernel 0: transpose W [D][C] -> Wt [C][D] (workspace). 7680 float4 chunks of
// Wt; each thread gathers 4 column elements (L2-resident scalar reads) and
// writes one coalesced float4. ~1 µs, runs once.
// ---------------------------------------------------------------------------
__global__ __launch_bounds__(256) void transpose_kernel(
        const float* __restrict__ W, float* __restrict__ Wt) {
    const int c = blockIdx.x * 256 + threadIdx.x;   // chunk id, NC*ND/4 total
    if (c >= (NC * ND) / 4) return;
    const int k = c / (ND / 4);
    const int m = c - k * (ND / 4);                 // d-chunk within column k
    float4 v;
    v.x = W[(4 * m + 0) * NC + k];
    v.y = W[(4 * m + 1) * NC + k];
    v.z = W[(4 * m + 2) * NC + k];
    v.w = W[(4 * m + 3) * NC + k];
    reinterpret_cast<float4*>(Wt)[c] = v;
}

// ---------------------------------------------------------------------------
// Kernel 1: G = W^T W (10x10) from Wt — contiguous row reads, fully coalesced.
// ---------------------------------------------------------------------------
__global__ __launch_bounds__(256) void gram_kernel(
        const float* __restrict__ Wt, float* __restrict__ G) {
    const int j = blockIdx.x / NC;
    const int k = blockIdx.x % NC;
    const float4* a = reinterpret_cast<const float4*>(Wt + j * ND);
    const float4* b = reinterpret_cast<const float4*>(Wt + k * ND);
    float acc = 0.0f;
    for (int i = threadIdx.x; i < ND / 4; i += 256) {
        const float4 av = a[i], bv = b[i];
        acc += av.x * bv.x + av.y * bv.y + av.z * bv.z + av.w * bv.w;
    }
    #pragma unroll
    for (int off = 32; off > 0; off >>= 1) acc += __shfl_xor(acc, off, 64);
    __shared__ float part[4];
    if ((threadIdx.x & 63) == 0) part[threadIdx.x >> 6] = acc;
    __syncthreads();
    if (threadIdx.x == 0) G[blockIdx.x] = part[0] + part[1] + part[2] + part[3];
}

// ---------------------------------------------------------------------------
// Kernel 2: main. Block = 1024 threads = 16 waves (max the 120 KB LDS allows),
// grid = 256 (1 block/CU). Wave PAIR (2q, 2q+1) co-owns 2 samples; each wave
// covers half of D (6 iters of 256 floats). This doubles resident waves vs the
// 512-thread version (latency hiding) while keeping the 2-samples-per-W-read
// amortization of LDS traffic. Staging is now a pure coalesced float4 copy
// from the pre-transposed Wt (conflict-free ds_write_b128).
// ---------------------------------------------------------------------------
__global__ __launch_bounds__(1024, 4) void jacreg_kernel(
        const float* __restrict__ data, const float* __restrict__ Wt,
        const float* __restrict__ G, float* __restrict__ out) {
    __shared__ float Wts[NC * ND];     // 122880 B, k-major: Wts[k*ND + d]
    __shared__ float Gs[100];
    __shared__ float pzs[16][24];      // per-wave partial z, 12-float stride/sample
    __shared__ float regs[16];

    const int tid  = threadIdx.x;
    const int lane = tid & 63;
    const int wv   = tid >> 6;         // 0..15
    const int q    = wv >> 1;          // pair id 0..7
    const int half = wv & 1;           // which D-half this wave covers

    if (tid < 100) Gs[tid] = G[tid];

    const int s0 = blockIdx.x * 16 + q * 2;          // pair's 2 samples
    const float* __restrict__ r0 = data + (size_t)s0 * ND + half * (ND / 2);
    const float* __restrict__ r1 = r0 + ND;

    // Issue first-iteration data loads BEFORE staging so HBM latency overlaps
    // the W copy.
    float4 x0 = reinterpret_cast<const float4*>(r0)[lane];
    float4 x1 = reinterpret_cast<const float4*>(r1)[lane];

    // Stage Wt -> LDS: coalesced float4 reads, conflict-free b128 writes.
    {
        const float4* src = reinterpret_cast<const float4*>(Wt);
        float4* dst = reinterpret_cast<float4*>(Wts);
        #pragma unroll
        for (int i = 0; i < 8; ++i) {
            const int c = tid + i * 1024;
            if (c < (NC * ND) / 4) dst[c] = src[c];
        }
    }
    __syncthreads();

    float acc[2][NC];
    #pragma unroll
    for (int s = 0; s < 2; ++s)
        #pragma unroll
        for (int k = 0; k < NC; ++k) acc[s][k] = 0.0f;

    const int dbase0 = half * (ND / 2);
    #pragma unroll
    for (int it = 0; it < 6; ++it) {
        const int nit = (it == 5) ? 5 : it + 1;      // 1-ahead prefetch
        const float4 nx0 = reinterpret_cast<const float4*>(r0)[nit * 64 + lane];
        const float4 nx1 = reinterpret_cast<const float4*>(r1)[nit * 64 + lane];

        const int dbase = dbase0 + it * 256 + lane * 4;
        #pragma unroll
        for (int k = 0; k < NC; ++k) {
            const float4 wt = *reinterpret_cast<const float4*>(&Wts[k * ND + dbase]);
            acc[0][k] = fmaf(x0.x, wt.x, acc[0][k]);
            acc[0][k] = fmaf(x0.y, wt.y, acc[0][k]);
            acc[0][k] = fmaf(x0.z, wt.z, acc[0][k]);
            acc[0][k] = fmaf(x0.w, wt.w, acc[0][k]);
            acc[1][k] = fmaf(x1.x, wt.x, acc[1][k]);
            acc[1][k] = fmaf(x1.y, wt.y, acc[1][k]);
            acc[1][k] = fmaf(x1.z, wt.z, acc[1][k]);
            acc[1][k] = fmaf(x1.w, wt.w, acc[1][k]);
        }
        x0 = nx0;
        x1 = nx1;
    }

    // In-wave butterfly: every lane ends with this wave's full D-half partial.
    #pragma unroll
    for (int s = 0; s < 2; ++s)
        #pragma unroll
        for (int k = 0; k < NC; ++k) {
            float v = acc[s][k];
            #pragma unroll
            for (int off = 32; off > 0; off >>= 1) v += __shfl_xor(v, off, 64);
            acc[s][k] = v;
        }

    // Lane 0 publishes the wave's partials (vectorized, static reg indexing).
    if (lane == 0) {
        float4* p = reinterpret_cast<float4*>(&pzs[wv][0]);
        p[0] = make_float4(acc[0][0], acc[0][1], acc[0][2], acc[0][3]);
        p[1] = make_float4(acc[0][4], acc[0][5], acc[0][6], acc[0][7]);
        p[2] = make_float4(acc[0][8], acc[0][9], 0.0f, 0.0f);
        p[3] = make_float4(acc[1][0], acc[1][1], acc[1][2], acc[1][3]);
        p[4] = make_float4(acc[1][4], acc[1][5], acc[1][6], acc[1][7]);
        p[5] = make_float4(acc[1][8], acc[1][9], 0.0f, 0.0f);
    }
    __syncthreads();

    // Analytic epilogue on the even wave of each pair: lane 0 -> sample s0,
    // lane 1 -> sample s0+1. z = sum of the two waves' D-half partials.
    if (half == 0 && lane < 2) {
        float z[NC];
        #pragma unroll
        for (int k = 0; k < NC; ++k)
            z[k] = pzs[wv][lane * 12 + k] + pzs[wv + 1][lane * 12 + k];

        float zm = z[0];
        #pragma unroll
        for (int k = 1; k < NC; ++k) zm = fmaxf(zm, z[k]);
        float e[NC], Zs = 0.0f;
        #pragma unroll
        for (int k = 0; k < NC; ++k) { e[k] = expf(z[k] - zm); Zs += e[k]; }
        const float inv = 1.0f / Zs;

        float sg[NC], p[NC], sq[NC], u[NC];
        #pragma unroll
        for (int k = 0; k < NC; ++k) {
            sg[k] = e[k] * inv;                 // softmax probs (sigma)
            p[k]  = kAlpha * sg[k] + kNumStab;  // stabilized probs
            sq[k] = sqrtf(p[k]);                // s
            u[k]  = sg[k] / sq[k];              // sigma / s
        }
        const float qd = 1.0f - sq[NM];

        // v = G*sigma, t = sigma^T G sigma
        float v[NC], t = 0.0f;
        #pragma unroll
        for (int k = 0; k < NC; ++k) {
            float a = 0.0f;
            #pragma unroll
            for (int j = 0; j < NC; ++j) a = fmaf(Gs[k * NC + j], sg[j], a);
            v[k] = a;
            t = fmaf(sg[k], a, t);
        }
        const float vM = v[NM], uM = u[NM];
        const float QMM = Gs[NC * NC - 1] - 2.0f * vM + t;

        float sumJ = 0.0f;
        #pragma unroll
        for (int i = 0; i < NM; ++i) {
            const float Qii = Gs[i * NC + i] - 2.0f * v[i] + t;
            const float QiM = Gs[i * NC + NM] - v[i] - vM + t;
            const float r = sq[i] / qd;
            sumJ += u[i] * u[i] * Qii
                  + 2.0f * u[i] * uM * r * QiM
                  + uM * uM * r * r * QMM;
        }
        const float jn = (kAlpha / qd) * sqrtf(fmaxf(sumJ, 0.0f));

        float ssum = 0.0f;
        #pragma unroll
        for (int k = 0; k < NC; ++k) ssum += sq[k];
        const float ac = fminf(1.0f, fmaxf(-1.0f, ssum * kInvSqrtC));
        const float delta = 2.0f * acosf(ac);

        float psum = 0.0f;
        #pragma unroll
        for (int k = 0; k < NM; ++k) psum += p[k];
        const float rho = (2.0f * qd - psum) / qd;

        const float a = jn - delta / (rho * kEps);
        regs[q * 2 + lane] = (a > 0.0f) ? a : expm1f(a);
    }
    __syncthreads();
    if (tid == 0) {
        float bs = 0.0f;
        #pragma unroll
        for (int i = 0; i < 16; ++i) bs += regs[i];
        atomicAdd(out, bs * (1.0f / (float)NB));
    }
}

extern "C" void kernel_launch(void* const* d_in, const int* in_sizes, int n_in,
                              void* d_out, int out_size, void* d_ws, size_t ws_size,
                              hipStream_t stream) {
    const float* data = (const float*)d_in[0];
    const float* W    = (const float*)d_in[1];
    float* out = (float*)d_out;
    float* Wt  = (float*)d_ws;            // NC*ND floats (120 KB)
    float* G   = Wt + NC * ND;            // 100 floats

    // d_out is re-poisoned before every timed launch -> zero it ourselves.
    hipMemsetAsync(out, 0, sizeof(float), stream);
    transpose_kernel<<<(NC * ND / 4 + 255) / 256, 256, 0, stream>>>(W, Wt);
    gram_kernel<<<NC * NC, 256, 0, stream>>>(Wt, G);
    jacreg_kernel<<<NB / 16, 1024, 0, stream>>>(data, Wt, G, out);
}

// Round 10
// 106.682 us; speedup vs baseline: 1.0049x; 1.0049x over previous
//
#include <hip/hip_runtime.h>
#include <math.h>

// Problem constants (B, D, C) from the reference.
#define NB 4096
#define ND 3072
#define NC 10
#define NM 9          // C-1
#define WSTRIDE 3076  // ND+4: k-major LDS row stride. 3072%32==0 put every k of a
                      // given d in one bank (~10-way scatter-write conflicts);
                      // 3076%32==4 spreads k across 8 banks. 16B-aligned (3076*4).

static constexpr float kEps      = 0.1f;
static constexpr float kNumStab  = 1e-6f;
static constexpr float kAlpha    = 1.0f - (float)NC * kNumStab;  // 1 - C*num_stab
static constexpr float kInvSqrtC = 0.31622776601683794f;         // 1/sqrt(10)

// ---------------------------------------------------------------------------
// Single fused kernel. Block = 1024 threads = 16 waves, grid = 256 (1 block/CU,
// forced by 123 KB LDS). Wave PAIR (2q, 2q+1) co-owns 2 samples; each wave
// covers half of D (6 iters of 256 floats). The 10x10 Gram is computed per
// block from the staged LDS Wt (~1 µs) instead of separate kernels -> the
// whole problem is ONE launch + the 4-byte memset. No d_ws use: the harness's
// 256 MB workspace re-poison has nothing to serialize against.
// ---------------------------------------------------------------------------
__global__ __launch_bounds__(1024) void fused_kernel(
        const float* __restrict__ data, const float* __restrict__ W,
        float* __restrict__ out) {
    __shared__ float Wts[NC * WSTRIDE];  // 123040 B, k-major: Wts[k*WSTRIDE + d]
    __shared__ float Gs[112];            // 10x10 Gram (padded)
    __shared__ float pzs[16][24];        // per-wave partial z, 12-float stride/sample
    __shared__ float regs[16];

    const int tid  = threadIdx.x;
    const int lane = tid & 63;
    const int wv   = tid >> 6;           // 0..15
    const int q    = wv >> 1;            // pair id 0..7
    const int half = wv & 1;             // which D-half this wave covers

    const int s0 = blockIdx.x * 16 + q * 2;          // pair's 2 samples
    const float* __restrict__ r0 = data + (size_t)s0 * ND + half * (ND / 2);
    const float* __restrict__ r1 = r0 + ND;

    // Depth-2 prologue loads: HBM latency hides under the W staging below.
    float4 xa0 = reinterpret_cast<const float4*>(r0)[lane];
    float4 xa1 = reinterpret_cast<const float4*>(r1)[lane];
    float4 xb0 = reinterpret_cast<const float4*>(r0)[64 + lane];
    float4 xb1 = reinterpret_cast<const float4*>(r1)[64 + lane];

    // Stage W -> LDS transposed. Coalesced float4 global reads; scattered
    // one-time scalar LDS writes (30/thread), de-conflicted by WSTRIDE.
    {
        const float4* W4 = reinterpret_cast<const float4*>(W);
        #pragma unroll
        for (int i = 0; i < 8; ++i) {
            const int c = tid + i * 1024;
            if (c < (ND * NC) / 4) {
                const float4 w4 = W4[c];
                const float* wp = reinterpret_cast<const float*>(&w4);
                const int e0 = c * 4;
                #pragma unroll
                for (int j = 0; j < 4; ++j) {
                    const int e = e0 + j;
                    Wts[(e % NC) * WSTRIDE + (e / NC)] = wp[j];
                }
            }
        }
    }
    __syncthreads();

    // Per-block Gram from staged Wt: wave wv owns entries wv*7 .. wv*7+6.
    // ~168 conflict-free ds_read_b128 per wave; overlaps other waves' work.
    #pragma unroll
    for (int n = 0; n < 7; ++n) {
        const int e = wv * 7 + n;
        if (e < NC * NC) {
            const int gj = e / NC, gk = e % NC;
            float a = 0.0f;
            #pragma unroll
            for (int c = 0; c < 12; ++c) {
                const float4 aj = *reinterpret_cast<const float4*>(
                    &Wts[gj * WSTRIDE + c * 256 + lane * 4]);
                const float4 bk = *reinterpret_cast<const float4*>(
                    &Wts[gk * WSTRIDE + c * 256 + lane * 4]);
                a += aj.x * bk.x + aj.y * bk.y + aj.z * bk.z + aj.w * bk.w;
            }
            #pragma unroll
            for (int off = 32; off > 0; off >>= 1) a += __shfl_xor(a, off, 64);
            if (lane == 0) Gs[e] = a;
        }
    }
    // No barrier here: the epilogue's Gs reads are ordered by the pzs barrier.

    float acc[2][NC];
    #pragma unroll
    for (int s = 0; s < 2; ++s)
        #pragma unroll
        for (int k = 0; k < NC; ++k) acc[s][k] = 0.0f;

    const int dbase0 = half * (ND / 2);
    #pragma unroll
    for (int it = 0; it < 6; ++it) {
        // Rotate a depth-2 data prefetch pipeline (all static indexing).
        float4 xc0 = xb0, xc1 = xb1;
        if (it < 4) {
            xc0 = reinterpret_cast<const float4*>(r0)[(it + 2) * 64 + lane];
            xc1 = reinterpret_cast<const float4*>(r1)[(it + 2) * 64 + lane];
        }

        const int dbase = dbase0 + it * 256 + lane * 4;
        #pragma unroll
        for (int k = 0; k < NC; ++k) {
            const float4 wt = *reinterpret_cast<const float4*>(&Wts[k * WSTRIDE + dbase]);
            acc[0][k] = fmaf(xa0.x, wt.x, acc[0][k]);
            acc[0][k] = fmaf(xa0.y, wt.y, acc[0][k]);
            acc[0][k] = fmaf(xa0.z, wt.z, acc[0][k]);
            acc[0][k] = fmaf(xa0.w, wt.w, acc[0][k]);
            acc[1][k] = fmaf(xa1.x, wt.x, acc[1][k]);
            acc[1][k] = fmaf(xa1.y, wt.y, acc[1][k]);
            acc[1][k] = fmaf(xa1.z, wt.z, acc[1][k]);
            acc[1][k] = fmaf(xa1.w, wt.w, acc[1][k]);
        }
        xa0 = xb0; xa1 = xb1;
        xb0 = xc0; xb1 = xc1;
    }

    // In-wave butterfly: every lane ends with this wave's full D-half partial.
    #pragma unroll
    for (int s = 0; s < 2; ++s)
        #pragma unroll
        for (int k = 0; k < NC; ++k) {
            float v = acc[s][k];
            #pragma unroll
            for (int off = 32; off > 0; off >>= 1) v += __shfl_xor(v, off, 64);
            acc[s][k] = v;
        }

    // Lane 0 publishes the wave's partials (vectorized, static reg indexing).
    if (lane == 0) {
        float4* p = reinterpret_cast<float4*>(&pzs[wv][0]);
        p[0] = make_float4(acc[0][0], acc[0][1], acc[0][2], acc[0][3]);
        p[1] = make_float4(acc[0][4], acc[0][5], acc[0][6], acc[0][7]);
        p[2] = make_float4(acc[0][8], acc[0][9], 0.0f, 0.0f);
        p[3] = make_float4(acc[1][0], acc[1][1], acc[1][2], acc[1][3]);
        p[4] = make_float4(acc[1][4], acc[1][5], acc[1][6], acc[1][7]);
        p[5] = make_float4(acc[1][8], acc[1][9], 0.0f, 0.0f);
    }
    __syncthreads();

    // Analytic epilogue on the even wave of each pair: lane 0 -> sample s0,
    // lane 1 -> sample s0+1. z = sum of the two waves' D-half partials.
    if (half == 0 && lane < 2) {
        float z[NC];
        #pragma unroll
        for (int k = 0; k < NC; ++k)
            z[k] = pzs[wv][lane * 12 + k] + pzs[wv + 1][lane * 12 + k];

        float zm = z[0];
        #pragma unroll
        for (int k = 1; k < NC; ++k) zm = fmaxf(zm, z[k]);
        float e[NC], Zs = 0.0f;
        #pragma unroll
        for (int k = 0; k < NC; ++k) { e[k] = expf(z[k] - zm); Zs += e[k]; }
        const float inv = 1.0f / Zs;

        float sg[NC], p[NC], sq[NC], u[NC];
        #pragma unroll
        for (int k = 0; k < NC; ++k) {
            sg[k] = e[k] * inv;                 // softmax probs (sigma)
            p[k]  = kAlpha * sg[k] + kNumStab;  // stabilized probs
            sq[k] = sqrtf(p[k]);                // s
            u[k]  = sg[k] / sq[k];              // sigma / s
        }
        const float qd = 1.0f - sq[NM];

        // v = G*sigma, t = sigma^T G sigma
        float v[NC], t = 0.0f;
        #pragma unroll
        for (int k = 0; k < NC; ++k) {
            float a = 0.0f;
            #pragma unroll
            for (int j = 0; j < NC; ++j) a = fmaf(Gs[k * NC + j], sg[j], a);
            v[k] = a;
            t = fmaf(sg[k], a, t);
        }
        const float vM = v[NM], uM = u[NM];
        const float QMM = Gs[NC * NC - 1] - 2.0f * vM + t;

        float sumJ = 0.0f;
        #pragma unroll
        for (int i = 0; i < NM; ++i) {
            const float Qii = Gs[i * NC + i] - 2.0f * v[i] + t;
            const float QiM = Gs[i * NC + NM] - v[i] - vM + t;
            const float r = sq[i] / qd;
            sumJ += u[i] * u[i] * Qii
                  + 2.0f * u[i] * uM * r * QiM
                  + uM * uM * r * r * QMM;
        }
        const float jn = (kAlpha / qd) * sqrtf(fmaxf(sumJ, 0.0f));

        float ssum = 0.0f;
        #pragma unroll
        for (int k = 0; k < NC; ++k) ssum += sq[k];
        const float ac = fminf(1.0f, fmaxf(-1.0f, ssum * kInvSqrtC));
        const float delta = 2.0f * acosf(ac);

        float psum = 0.0f;
        #pragma unroll
        for (int k = 0; k < NM; ++k) psum += p[k];
        const float rho = (2.0f * qd - psum) / qd;

        const float a = jn - delta / (rho * kEps);
        regs[q * 2 + lane] = (a > 0.0f) ? a : expm1f(a);
    }
    __syncthreads();
    if (tid == 0) {
        float bs = 0.0f;
        #pragma unroll
        for (int i = 0; i < 16; ++i) bs += regs[i];
        atomicAdd(out, bs * (1.0f / (float)NB));
    }
}

extern "C" void kernel_launch(void* const* d_in, const int* in_sizes, int n_in,
                              void* d_out, int out_size, void* d_ws, size_t ws_size,
                              hipStream_t stream) {
    const float* data = (const float*)d_in[0];
    const float* W    = (const float*)d_in[1];
    float* out = (float*)d_out;

    // d_out is re-poisoned to 0xAA before every timed launch -> zero it ourselves.
    hipMemsetAsync(out, 0, sizeof(float), stream);
    fused_kernel<<<NB / 16, 1024, 0, stream>>>(data, W, out);
}

// Round 11
// 104.124 us; speedup vs baseline: 1.0296x; 1.0246x over previous
//
#include <hip/hip_runtime.h>
#include <math.h>

// Problem constants (B, D, C) from the reference.
#define NB 4096
#define ND 3072
#define NC 10
#define NM 9          // C-1
#define WSTRIDE 3076  // ND+4: k-major LDS row stride. 3072%32==0 put every k of a
                      // given d in one bank (~10-way scatter-write conflicts);
                      // 3076%32==4 spreads k across 8 banks. 16B-aligned (3076*4).

static constexpr float kEps      = 0.1f;
static constexpr float kNumStab  = 1e-6f;
static constexpr float kAlpha    = 1.0f - (float)NC * kNumStab;  // 1 - C*num_stab
static constexpr float kInvSqrtC = 0.31622776601683794f;         // 1/sqrt(10)

// ---------------------------------------------------------------------------
// Single fused kernel. Block = 1024 threads = 16 waves, grid = 256 (1 block/CU,
// forced by 123 KB LDS).
// R10 profile: kernel 50 µs, VALUBusy 23%, HBM 6%, VGPR=64 -> latency-bound.
// Fixes: (a) __launch_bounds__(1024,4): LDS caps us at 4 waves/SIMD anyway,
// so let the compiler use 128 VGPRs for deeper load pipelining (was capped at
// 64 for an unreachable 8-wave occupancy). (b) Gram restructure: wave j<10
// computes upper-triangle row (j,k>=j) reading row j ONCE per chunk ->
// 780 ds_read_b128/block vs 2688 (each wave previously re-read its pivot row
// 7x per chunk). Waves 10-15 skip straight to the main loop; ordering of Gs
// is guaranteed by the pzs __syncthreads before the epilogue reads it.
// ---------------------------------------------------------------------------
__global__ __launch_bounds__(1024, 4) void fused_kernel(
        const float* __restrict__ data, const float* __restrict__ W,
        float* __restrict__ out) {
    __shared__ float Wts[NC * WSTRIDE];  // 123040 B, k-major: Wts[k*WSTRIDE + d]
    __shared__ float Gs[112];            // 10x10 Gram (padded)
    __shared__ float pzs[16][24];        // per-wave partial z, 12-float stride/sample
    __shared__ float regs[16];

    const int tid  = threadIdx.x;
    const int lane = tid & 63;
    const int wv   = tid >> 6;           // 0..15
    const int q    = wv >> 1;            // pair id 0..7
    const int half = wv & 1;             // which D-half this wave covers

    const int s0 = blockIdx.x * 16 + q * 2;          // pair's 2 samples
    const float* __restrict__ r0 = data + (size_t)s0 * ND + half * (ND / 2);
    const float* __restrict__ r1 = r0 + ND;

    // Depth-2 prologue loads: HBM latency hides under the W staging below.
    float4 xa0 = reinterpret_cast<const float4*>(r0)[lane];
    float4 xa1 = reinterpret_cast<const float4*>(r1)[lane];
    float4 xb0 = reinterpret_cast<const float4*>(r0)[64 + lane];
    float4 xb1 = reinterpret_cast<const float4*>(r1)[64 + lane];

    // Stage W -> LDS transposed. Coalesced float4 global reads; scattered
    // one-time scalar LDS writes (30/thread), de-conflicted by WSTRIDE.
    {
        const float4* W4 = reinterpret_cast<const float4*>(W);
        #pragma unroll
        for (int i = 0; i < 8; ++i) {
            const int c = tid + i * 1024;
            if (c < (ND * NC) / 4) {
                const float4 w4 = W4[c];
                const float* wp = reinterpret_cast<const float*>(&w4);
                const int e0 = c * 4;
                #pragma unroll
                for (int j = 0; j < 4; ++j) {
                    const int e = e0 + j;
                    Wts[(e % NC) * WSTRIDE + (e / NC)] = wp[j];
                }
            }
        }
    }
    __syncthreads();

    // Per-block Gram, row-shared: wave j computes G[j][k] for k>=j.
    // Row j is read once per chunk (not once per entry). 780 b128 reads/block.
    if (wv < NC) {
        const int gj = wv;
        float ga[NC];
        #pragma unroll
        for (int k = 0; k < NC; ++k) ga[k] = 0.0f;
        for (int c = 0; c < 12; ++c) {
            const float4 aj = *reinterpret_cast<const float4*>(
                &Wts[gj * WSTRIDE + c * 256 + lane * 4]);
            #pragma unroll
            for (int k = 0; k < NC; ++k) {
                if (k >= gj) {   // wave-uniform branch: cheap skip
                    const float4 bk = *reinterpret_cast<const float4*>(
                        &Wts[k * WSTRIDE + c * 256 + lane * 4]);
                    ga[k] += aj.x * bk.x + aj.y * bk.y + aj.z * bk.z + aj.w * bk.w;
                }
            }
        }
        #pragma unroll
        for (int k = 0; k < NC; ++k) {
            if (k >= gj) {
                float v = ga[k];
                #pragma unroll
                for (int off = 32; off > 0; off >>= 1) v += __shfl_xor(v, off, 64);
                if (lane == 0) { Gs[gj * NC + k] = v; Gs[k * NC + gj] = v; }
            }
        }
    }
    // No barrier here: the epilogue's Gs reads are ordered by the pzs barrier.

    float acc[2][NC];
    #pragma unroll
    for (int s = 0; s < 2; ++s)
        #pragma unroll
        for (int k = 0; k < NC; ++k) acc[s][k] = 0.0f;

    const int dbase0 = half * (ND / 2);
    #pragma unroll
    for (int it = 0; it < 6; ++it) {
        // Rotate a depth-2 data prefetch pipeline (all static indexing).
        float4 xc0 = xb0, xc1 = xb1;
        if (it < 4) {
            xc0 = reinterpret_cast<const float4*>(r0)[(it + 2) * 64 + lane];
            xc1 = reinterpret_cast<const float4*>(r1)[(it + 2) * 64 + lane];
        }

        const int dbase = dbase0 + it * 256 + lane * 4;
        #pragma unroll
        for (int k = 0; k < NC; ++k) {
            const float4 wt = *reinterpret_cast<const float4*>(&Wts[k * WSTRIDE + dbase]);
            acc[0][k] = fmaf(xa0.x, wt.x, acc[0][k]);
            acc[0][k] = fmaf(xa0.y, wt.y, acc[0][k]);
            acc[0][k] = fmaf(xa0.z, wt.z, acc[0][k]);
            acc[0][k] = fmaf(xa0.w, wt.w, acc[0][k]);
            acc[1][k] = fmaf(xa1.x, wt.x, acc[1][k]);
            acc[1][k] = fmaf(xa1.y, wt.y, acc[1][k]);
            acc[1][k] = fmaf(xa1.z, wt.z, acc[1][k]);
            acc[1][k] = fmaf(xa1.w, wt.w, acc[1][k]);
        }
        xa0 = xb0; xa1 = xb1;
        xb0 = xc0; xb1 = xc1;
    }

    // In-wave butterfly: every lane ends with this wave's full D-half partial.
    #pragma unroll
    for (int s = 0; s < 2; ++s)
        #pragma unroll
        for (int k = 0; k < NC; ++k) {
            float v = acc[s][k];
            #pragma unroll
            for (int off = 32; off > 0; off >>= 1) v += __shfl_xor(v, off, 64);
            acc[s][k] = v;
        }

    // Lane 0 publishes the wave's partials (vectorized, static reg indexing).
    if (lane == 0) {
        float4* p = reinterpret_cast<float4*>(&pzs[wv][0]);
        p[0] = make_float4(acc[0][0], acc[0][1], acc[0][2], acc[0][3]);
        p[1] = make_float4(acc[0][4], acc[0][5], acc[0][6], acc[0][7]);
        p[2] = make_float4(acc[0][8], acc[0][9], 0.0f, 0.0f);
        p[3] = make_float4(acc[1][0], acc[1][1], acc[1][2], acc[1][3]);
        p[4] = make_float4(acc[1][4], acc[1][5], acc[1][6], acc[1][7]);
        p[5] = make_float4(acc[1][8], acc[1][9], 0.0f, 0.0f);
    }
    __syncthreads();

    // Analytic epilogue on the even wave of each pair: lane 0 -> sample s0,
    // lane 1 -> sample s0+1. z = sum of the two waves' D-half partials.
    if (half == 0 && lane < 2) {
        float z[NC];
        #pragma unroll
        for (int k = 0; k < NC; ++k)
            z[k] = pzs[wv][lane * 12 + k] + pzs[wv + 1][lane * 12 + k];

        float zm = z[0];
        #pragma unroll
        for (int k = 1; k < NC; ++k) zm = fmaxf(zm, z[k]);
        float e[NC], Zs = 0.0f;
        #pragma unroll
        for (int k = 0; k < NC; ++k) { e[k] = expf(z[k] - zm); Zs += e[k]; }
        const float inv = 1.0f / Zs;

        float sg[NC], p[NC], sq[NC], u[NC];
        #pragma unroll
        for (int k = 0; k < NC; ++k) {
            sg[k] = e[k] * inv;                 // softmax probs (sigma)
            p[k]  = kAlpha * sg[k] + kNumStab;  // stabilized probs
            sq[k] = sqrtf(p[k]);                // s
            u[k]  = sg[k] / sq[k];              // sigma / s
        }
        const float qd = 1.0f - sq[NM];

        // v = G*sigma, t = sigma^T G sigma
        float v[NC], t = 0.0f;
        #pragma unroll
        for (int k = 0; k < NC; ++k) {
            float a = 0.0f;
            #pragma unroll
            for (int j = 0; j < NC; ++j) a = fmaf(Gs[k * NC + j], sg[j], a);
            v[k] = a;
            t = fmaf(sg[k], a, t);
        }
        const float vM = v[NM], uM = u[NM];
        const float QMM = Gs[NC * NC - 1] - 2.0f * vM + t;

        float sumJ = 0.0f;
        #pragma unroll
        for (int i = 0; i < NM; ++i) {
            const float Qii = Gs[i * NC + i] - 2.0f * v[i] + t;
            const float QiM = Gs[i * NC + NM] - v[i] - vM + t;
            const float r = sq[i] / qd;
            sumJ += u[i] * u[i] * Qii
                  + 2.0f * u[i] * uM * r * QiM
                  + uM * uM * r * r * QMM;
        }
        const float jn = (kAlpha / qd) * sqrtf(fmaxf(sumJ, 0.0f));

        float ssum = 0.0f;
        #pragma unroll
        for (int k = 0; k < NC; ++k) ssum += sq[k];
        const float ac = fminf(1.0f, fmaxf(-1.0f, ssum * kInvSqrtC));
        const float delta = 2.0f * acosf(ac);

        float psum = 0.0f;
        #pragma unroll
        for (int k = 0; k < NM; ++k) psum += p[k];
        const float rho = (2.0f * qd - psum) / qd;

        const float a = jn - delta / (rho * kEps);
        regs[q * 2 + lane] = (a > 0.0f) ? a : expm1f(a);
    }
    __syncthreads();
    if (tid == 0) {
        float bs = 0.0f;
        #pragma unroll
        for (int i = 0; i < 16; ++i) bs += regs[i];
        atomicAdd(out, bs * (1.0f / (float)NB));
    }
}

extern "C" void kernel_launch(void* const* d_in, const int* in_sizes, int n_in,
                              void* d_out, int out_size, void* d_ws, size_t ws_size,
                              hipStream_t stream) {
    const float* data = (const float*)d_in[0];
    const float* W    = (const float*)d_in[1];
    float* out = (float*)d_out;

    // d_out is re-poisoned to 0xAA before every timed launch -> zero it ourselves.
    hipMemsetAsync(out, 0, sizeof(float), stream);
    fused_kernel<<<NB / 16, 1024, 0, stream>>>(data, W, out);
}